// Round 1
// baseline (604.373 us; speedup 1.0000x reference)
//
#include <hip/hip_runtime.h>
#include <math.h>

// ---------------- small setup kernels ----------------

__global__ void zero_init_kernel(float* deg, float* gsum, float* gcnt, int N) {
  int i = blockIdx.x * blockDim.x + threadIdx.x;
  if (i < N) deg[i] = 0.0f;
  if (i < 64) { gsum[i] = 0.0f; gcnt[i] = 0.0f; }
}

__global__ void deg_kernel(const int* __restrict__ dst, float* deg, int E) {
  int e = blockIdx.x * blockDim.x + threadIdx.x;
  if (e < E) atomicAdd(&deg[dst[e]], 1.0f);
}

// deg (in-degree, float) -> indeg (int), dinv = 1/sqrt(deg+1)  (self-loop adds 1)
__global__ void dinv_kernel(float* deg_dinv, int* indeg, int N) {
  int i = blockIdx.x * blockDim.x + threadIdx.x;
  if (i < N) {
    float c = deg_dinv[i];
    indeg[i] = (int)c;                  // counts are small ints, exact in fp32
    deg_dinv[i] = 1.0f / sqrtf(c + 1.0f);
  }
}

__global__ void blocksum_kernel(const int* __restrict__ indeg, int* bsum, int N) {
  __shared__ int s[256];
  int i = blockIdx.x * 256 + threadIdx.x;
  s[threadIdx.x] = (i < N) ? indeg[i] : 0;
  __syncthreads();
  for (int off = 128; off > 0; off >>= 1) {
    if (threadIdx.x < off) s[threadIdx.x] += s[threadIdx.x + off];
    __syncthreads();
  }
  if (threadIdx.x == 0) bsum[blockIdx.x] = s[0];
}

__global__ void scan_bsum_kernel(int* bsum, int nb) {
  __shared__ int s[1024];
  for (int q = threadIdx.x; q < nb; q += blockDim.x) s[q] = bsum[q];
  __syncthreads();
  if (threadIdx.x == 0) {
    int run = 0;
    for (int j = 0; j < nb; ++j) { int t = s[j]; s[j] = run; run += t; }
  }
  __syncthreads();
  for (int q = threadIdx.x; q < nb; q += blockDim.x) bsum[q] = s[q];
}

// indeg/cursor alias the same buffer: read own element, then overwrite. Safe.
__global__ void rowptr_kernel(const int* __restrict__ indeg, const int* __restrict__ bsum,
                              int* row_ptr, int* cursor, int N, int E) {
  __shared__ int s[256];
  int t = threadIdx.x;
  int i = blockIdx.x * 256 + t;
  int val = (i < N) ? indeg[i] : 0;
  s[t] = val;
  __syncthreads();
  for (int off = 1; off < 256; off <<= 1) {
    int x = (t >= off) ? s[t - off] : 0;
    __syncthreads();
    s[t] += x;
    __syncthreads();
  }
  int excl = s[t] - val + bsum[blockIdx.x];
  if (i < N) { row_ptr[i] = excl; cursor[i] = excl; }
  if (blockIdx.x == 0 && t == 0) row_ptr[N] = E;
}

__global__ void fill_kernel(const int* __restrict__ src, const int* __restrict__ dst,
                            const float* __restrict__ dinv, int* cursor,
                            int* col_src, float* w_srt, int E) {
  int e = blockIdx.x * blockDim.x + threadIdx.x;
  if (e < E) {
    int s = src[e], d = dst[e];
    int p = atomicAdd(&cursor[d], 1);
    col_src[p] = s;
    w_srt[p] = dinv[s] * dinv[d];
  }
}

// ---------------- layer 1: aggregate x (9-wide), then GEMM 9x128 ----------------

__global__ void agg9_kernel(const float* __restrict__ x, const float* __restrict__ dinv,
                            const int* __restrict__ row_ptr, const int* __restrict__ col_src,
                            const float* __restrict__ w_srt, float* xa, int N) {
  int i = blockIdx.x * blockDim.x + threadIdx.x;
  if (i >= N) return;
  float di = dinv[i], sw = di * di;
  float acc[9];
#pragma unroll
  for (int f = 0; f < 9; ++f) acc[f] = x[i * 9 + f] * sw;   // self-loop term
  int rs = row_ptr[i], re = row_ptr[i + 1];
  for (int e = rs; e < re; ++e) {
    int s = col_src[e];
    float w = w_srt[e];
    const float* xp = x + (size_t)s * 9;
#pragma unroll
    for (int f = 0; f < 9; ++f) acc[f] += xp[f] * w;
  }
#pragma unroll
  for (int f = 0; f < 9; ++f) xa[(size_t)i * 9 + f] = acc[f];
}

__global__ void gemm1_kernel(const float* __restrict__ xa, const float* __restrict__ W1,
                             const float* __restrict__ b1, float* hA, int N) {
  __shared__ float sW[9 * 128];
  __shared__ float sb[128];
  __shared__ float sx[16 * 9];
  int tid = threadIdx.x;
  int rb = blockIdx.x * 16;
  for (int q = tid; q < 9 * 128; q += 256) sW[q] = W1[q];
  if (tid < 128) sb[tid] = b1[tid];
  for (int q = tid; q < 16 * 9; q += 256) {
    long gi = (long)rb * 9 + q;
    sx[q] = (gi < (long)N * 9) ? xa[gi] : 0.0f;
  }
  __syncthreads();
  int col = tid & 127, rsub = tid >> 7;
  for (int j = 0; j < 8; ++j) {
    int rl = j * 2 + rsub;
    int row = rb + rl;
    if (row < N) {
      float s = sb[col];
#pragma unroll
      for (int f = 0; f < 9; ++f) s += sx[rl * 9 + f] * sW[f * 128 + col];
      hA[(size_t)row * 128 + col] = fmaxf(s, 0.0f);   // relu(conv1)
    }
  }
}

// ---------------- layer 2 GEMM: t = h1 @ W2  (fp32, LDS-tiled 64x128) ----------------

__global__ __launch_bounds__(256) void gemm2_kernel(const float* __restrict__ hA,
                                                    const float* __restrict__ W2,
                                                    float* hB, int N) {
  __shared__ float Hs[32 * 68];    // [k][row], row-dim padded to 68 (16B-aligned, bank-spread)
  __shared__ float Ws[32 * 128];   // [k][col]
  int tid = threadIdx.x;
  int rb = blockIdx.x * 64;
  int tcol = tid & 15, trow = tid >> 4;   // 16x16 threads; thread tile 4 rows x 8 cols
  float acc[4][8];
#pragma unroll
  for (int r = 0; r < 4; ++r)
#pragma unroll
    for (int c = 0; c < 8; ++c) acc[r][c] = 0.0f;

  for (int kc = 0; kc < 128; kc += 32) {
#pragma unroll
    for (int j = 0; j < 2; ++j) {        // stage Hs transposed: 512 float4
      int q = tid + j * 256;
      int row = q >> 3;
      int kk = (q & 7) * 4;
      float4 vv = make_float4(0.f, 0.f, 0.f, 0.f);
      int grow = rb + row;
      if (grow < N) vv = *(const float4*)&hA[(size_t)grow * 128 + kc + kk];
      Hs[(kk + 0) * 68 + row] = vv.x;
      Hs[(kk + 1) * 68 + row] = vv.y;
      Hs[(kk + 2) * 68 + row] = vv.z;
      Hs[(kk + 3) * 68 + row] = vv.w;
    }
#pragma unroll
    for (int j = 0; j < 4; ++j) {        // stage Ws: 1024 float4
      int q = tid + j * 256;
      int kr = q >> 5;
      int c4 = (q & 31) * 4;
      *(float4*)&Ws[kr * 128 + c4] = *(const float4*)&W2[(size_t)(kc + kr) * 128 + c4];
    }
    __syncthreads();
#pragma unroll 8
    for (int kk = 0; kk < 32; ++kk) {
      float4 a = *(const float4*)&Hs[kk * 68 + trow * 4];
      float4 b0 = *(const float4*)&Ws[kk * 128 + tcol * 8];
      float4 b1v = *(const float4*)&Ws[kk * 128 + tcol * 8 + 4];
      float av[4] = {a.x, a.y, a.z, a.w};
      float bv[8] = {b0.x, b0.y, b0.z, b0.w, b1v.x, b1v.y, b1v.z, b1v.w};
#pragma unroll
      for (int r = 0; r < 4; ++r)
#pragma unroll
        for (int c = 0; c < 8; ++c) acc[r][c] += av[r] * bv[c];
    }
    __syncthreads();
  }
#pragma unroll
  for (int r = 0; r < 4; ++r) {
    int row = rb + trow * 4 + r;
    if (row < N) {
      float4 o0 = make_float4(acc[r][0], acc[r][1], acc[r][2], acc[r][3]);
      float4 o1 = make_float4(acc[r][4], acc[r][5], acc[r][6], acc[r][7]);
      *(float4*)&hB[(size_t)row * 128 + tcol * 8] = o0;
      *(float4*)&hB[(size_t)row * 128 + tcol * 8 + 4] = o1;
    }
  }
}

// ---------------- collapsed head: v = W3 @ lin_w, c0 = b3.lin_w + lin_b ----------------

__global__ void vc0_kernel(const float* __restrict__ W3, const float* __restrict__ b3,
                           const float* __restrict__ lin_w, const float* __restrict__ lin_b,
                           float* v, float* c0) {
  __shared__ float slw[128];
  __shared__ float red[128];
  int t = threadIdx.x;   // 128 threads
  slw[t] = lin_w[t];
  __syncthreads();
  float s = 0.0f;
  for (int c = 0; c < 128; ++c) s += W3[t * 128 + c] * slw[c];
  v[t] = s;
  red[t] = b3[t] * slw[t];
  __syncthreads();
  for (int off = 64; off > 0; off >>= 1) {
    if (t < off) red[t] += red[t + off];
    __syncthreads();
  }
  if (t == 0) c0[0] = red[0] + lin_b[0];
}

// ---------------- layer 2 aggregation (128-wide, wave/node) fused with z = relu(.)·v ----------------

__global__ __launch_bounds__(256) void agg128_kernel(const float* __restrict__ t,
    const float* __restrict__ dinv, const int* __restrict__ row_ptr,
    const int* __restrict__ col_src, const float* __restrict__ w_srt,
    const float* __restrict__ b2, const float* __restrict__ v, float* z, int N) {
  int wave = threadIdx.x >> 6;
  int lane = threadIdx.x & 63;
  int i = blockIdx.x * 4 + wave;
  if (i >= N) return;                      // wave-uniform exit, no syncthreads below
  float di = dinv[i], sw = di * di;
  const float* ti = t + (size_t)i * 128;
  float acc0 = ti[lane] * sw;              // self-loop
  float acc1 = ti[lane + 64] * sw;
  int rs = row_ptr[i], re = row_ptr[i + 1];
  for (int e = rs; e < re; ++e) {
    int s = col_src[e];
    float w = w_srt[e];
    const float* tp = t + (size_t)s * 128;
    acc0 += tp[lane] * w;                  // coalesced 512B row gather
    acc1 += tp[lane + 64] * w;
  }
  float h0 = fmaxf(acc0 + b2[lane], 0.0f);
  float h1 = fmaxf(acc1 + b2[lane + 64], 0.0f);
  float p = h0 * v[lane] + h1 * v[lane + 64];
#pragma unroll
  for (int off = 32; off > 0; off >>= 1) p += __shfl_down(p, off, 64);
  if (lane == 0) z[i] = p;                 // h2 never materialized
}

// ---------------- layer 3 (scalar) aggregation + mean-pool binning ----------------

__global__ void agg1_pool_kernel(const float* __restrict__ z, const float* __restrict__ dinv,
    const int* __restrict__ row_ptr, const int* __restrict__ col_src,
    const float* __restrict__ w_srt, const int* __restrict__ batch,
    float* gsum, float* gcnt, int N) {
  __shared__ float lsum[64];
  __shared__ float lcnt[64];
  int t = threadIdx.x;
  if (t < 64) { lsum[t] = 0.0f; lcnt[t] = 0.0f; }
  __syncthreads();
  int i = blockIdx.x * blockDim.x + t;
  if (i < N) {
    float di = dinv[i];
    float acc = z[i] * di * di;
    int rs = row_ptr[i], re = row_ptr[i + 1];
    for (int e = rs; e < re; ++e) acc += z[col_src[e]] * w_srt[e];
    int g = batch[i];
    atomicAdd(&lsum[g], acc);
    atomicAdd(&lcnt[g], 1.0f);
  }
  __syncthreads();
  if (t < 64 && lcnt[t] != 0.0f) {
    atomicAdd(&gsum[t], lsum[t]);
    atomicAdd(&gcnt[t], lcnt[t]);
  }
}

__global__ void final_kernel(const float* __restrict__ gsum, const float* __restrict__ gcnt,
                             const float* __restrict__ c0, float* out, int G) {
  int g = threadIdx.x;
  if (g < G) out[g] = gsum[g] / fmaxf(gcnt[g], 1.0f) + c0[0];
}

// ---------------- launch ----------------

extern "C" void kernel_launch(void* const* d_in, const int* in_sizes, int n_in,
                              void* d_out, int out_size, void* d_ws, size_t ws_size,
                              hipStream_t stream) {
  const float* x      = (const float*)d_in[0];
  const int*   eidx   = (const int*)d_in[1];
  const int*   batch  = (const int*)d_in[2];
  const float* W1     = (const float*)d_in[3];
  const float* b1     = (const float*)d_in[4];
  const float* W2     = (const float*)d_in[5];
  const float* b2     = (const float*)d_in[6];
  const float* W3     = (const float*)d_in[7];
  const float* b3     = (const float*)d_in[8];
  const float* lin_w  = (const float*)d_in[9];
  const float* lin_b  = (const float*)d_in[10];
  float* out = (float*)d_out;

  int N = in_sizes[0] / 9;
  int E = in_sizes[1] / 2;
  int G = out_size;
  const int* src = eidx;
  const int* dst = eidx + E;

  char* w = (char*)d_ws;
  size_t off = 0;
  auto alloc = [&](size_t bytes) -> void* {
    void* p = w + off;
    off += bytes;
    off = (off + 255) & ~(size_t)255;
    return p;
  };

  int nb = (N + 255) / 256;
  float* dinv   = (float*)alloc((size_t)N * 4);          // deg, then dinv (in-place)
  int*   rowptr = (int*)  alloc((size_t)(N + 1) * 4);
  int*   cursor = (int*)  alloc((size_t)N * 4);          // indeg, then fill cursor
  int*   bsum   = (int*)  alloc((size_t)nb * 4);
  int*   colsrc = (int*)  alloc((size_t)E * 4);
  float* wsrt   = (float*)alloc((size_t)E * 4);
  float* xa     = (float*)alloc((size_t)N * 9 * 4);
  float* hA     = (float*)alloc((size_t)N * 128 * 4);    // h1
  float* hB     = (float*)alloc((size_t)N * 128 * 4);    // t = h1 @ W2
  float* z      = (float*)alloc((size_t)N * 4);
  float* v      = (float*)alloc(128 * 4);
  float* c0     = (float*)alloc(4);
  float* gsum   = (float*)alloc(64 * 4);
  float* gcnt   = (float*)alloc(64 * 4);

  zero_init_kernel<<<nb, 256, 0, stream>>>(dinv, gsum, gcnt, N);
  deg_kernel<<<(E + 255) / 256, 256, 0, stream>>>(dst, dinv, E);
  dinv_kernel<<<nb, 256, 0, stream>>>(dinv, cursor, N);
  blocksum_kernel<<<nb, 256, 0, stream>>>(cursor, bsum, N);
  scan_bsum_kernel<<<1, 256, 0, stream>>>(bsum, nb);
  rowptr_kernel<<<nb, 256, 0, stream>>>(cursor, bsum, rowptr, cursor, N, E);
  fill_kernel<<<(E + 255) / 256, 256, 0, stream>>>(src, dst, dinv, cursor, colsrc, wsrt, E);
  vc0_kernel<<<1, 128, 0, stream>>>(W3, b3, lin_w, lin_b, v, c0);
  agg9_kernel<<<nb, 256, 0, stream>>>(x, dinv, rowptr, colsrc, wsrt, xa, N);
  gemm1_kernel<<<(N + 15) / 16, 256, 0, stream>>>(xa, W1, b1, hA, N);
  gemm2_kernel<<<(N + 63) / 64, 256, 0, stream>>>(hA, W2, hB, N);
  agg128_kernel<<<(N + 3) / 4, 256, 0, stream>>>(hB, dinv, rowptr, colsrc, wsrt, b2, v, z, N);
  agg1_pool_kernel<<<nb, 256, 0, stream>>>(z, dinv, rowptr, colsrc, wsrt, batch, gsum, gcnt, N);
  final_kernel<<<1, 64, 0, stream>>>(gsum, gcnt, c0, out, G);
}

// Round 3
// 531.281 us; speedup vs baseline: 1.1376x; 1.1376x over previous
//
#include <hip/hip_runtime.h>
#include <math.h>

// ---------------- setup: zero deg/gsum/gcnt + collapsed head (v = W3@lin_w, c0) ----------------

__global__ void zero_init_kernel(float* deg, float* gsum, float* gcnt,
                                 const float* __restrict__ W3, const float* __restrict__ b3,
                                 const float* __restrict__ lin_w, const float* __restrict__ lin_b,
                                 float* v, float* c0, int N) {
  int i = blockIdx.x * blockDim.x + threadIdx.x;
  if (i < N) deg[i] = 0.0f;
  if (i < 64) { gsum[i] = 0.0f; gcnt[i] = 0.0f; }
  if (blockIdx.x == gridDim.x - 1) {
    int t = threadIdx.x;
    if (t < 128) {
      float s = 0.0f;
      for (int c = 0; c < 128; ++c) s = fmaf(W3[t * 128 + c], lin_w[c], s);
      v[t] = s;
    }
    if (t == 0) {
      float s = 0.0f;
      for (int c = 0; c < 128; ++c) s = fmaf(b3[c], lin_w[c], s);
      c0[0] = s + lin_b[0];
    }
  }
}

__global__ void deg_kernel(const int* __restrict__ dst, float* deg, int E) {
  int e = blockIdx.x * blockDim.x + threadIdx.x;
  if (e < E) atomicAdd(&deg[dst[e]], 1.0f);
}

// deg(float) -> indeg(int) + dinv = 1/sqrt(deg+1), fused per-block sum of indeg -> bsum
__global__ void dinv_bsum_kernel(float* deg_dinv, int* indeg, int* bsum, int N) {
  __shared__ int s[256];
  int t = threadIdx.x;
  int i = blockIdx.x * 256 + t;
  int c = 0;
  if (i < N) {
    float cf = deg_dinv[i];
    c = (int)cf;                        // counts are small ints, exact in fp32
    indeg[i] = c;
    deg_dinv[i] = 1.0f / sqrtf(cf + 1.0f);
  }
  s[t] = c;
  __syncthreads();
  for (int off = 128; off > 0; off >>= 1) {
    if (t < off) s[t] += s[t + off];
    __syncthreads();
  }
  if (t == 0) bsum[blockIdx.x] = s[0];
}

__global__ void scan_bsum_kernel(int* bsum, int nb) {
  __shared__ int s[1024];
  for (int q = threadIdx.x; q < nb; q += blockDim.x) s[q] = bsum[q];
  __syncthreads();
  if (threadIdx.x == 0) {
    int run = 0;
    for (int j = 0; j < nb; ++j) { int t = s[j]; s[j] = run; run += t; }
  }
  __syncthreads();
  for (int q = threadIdx.x; q < nb; q += blockDim.x) bsum[q] = s[q];
}

// indeg/cursor alias the same buffer: read own element, then overwrite. Safe.
__global__ void rowptr_kernel(const int* __restrict__ indeg, const int* __restrict__ bsum,
                              int* row_ptr, int* cursor, int N, int E) {
  __shared__ int s[256];
  int t = threadIdx.x;
  int i = blockIdx.x * 256 + t;
  int val = (i < N) ? indeg[i] : 0;
  s[t] = val;
  __syncthreads();
  for (int off = 1; off < 256; off <<= 1) {
    int x = (t >= off) ? s[t - off] : 0;
    __syncthreads();
    s[t] += x;
    __syncthreads();
  }
  int excl = s[t] - val + bsum[blockIdx.x];
  if (i < N) { row_ptr[i] = excl; cursor[i] = excl; }
  if (blockIdx.x == 0 && t == 0) row_ptr[N] = E;
}

// CSR fill with interleaved (src, weight) pack -> one 8B scattered store per edge
__global__ void fill_kernel(const int* __restrict__ src, const int* __restrict__ dst,
                            const float* __restrict__ dinv, int* cursor,
                            long long* __restrict__ epack, int E) {
  int e = blockIdx.x * blockDim.x + threadIdx.x;
  if (e < E) {
    int s = src[e], d = dst[e];
    int p = atomicAdd(&cursor[d], 1);
    unsigned int w = (unsigned int)__float_as_int(dinv[s] * dinv[d]);
    epack[p] = (long long)(((unsigned long long)w << 32) | (unsigned int)s);
  }
}

__device__ __forceinline__ int ep_src(long long p) { return (int)(unsigned int)p; }
__device__ __forceinline__ float ep_w(long long p) {
  return __int_as_float((int)(unsigned int)((unsigned long long)p >> 32));
}

// ---------------- layer 1 fused: xa = A_hat x (9-wide), h1 = relu(xa@W1 + b1) ----------------

__global__ __launch_bounds__(256) void agg9_gemm1_kernel(const float* __restrict__ x,
    const float* __restrict__ dinv, const int* __restrict__ row_ptr,
    const long long* __restrict__ epack, const float* __restrict__ W1,
    const float* __restrict__ b1, float* __restrict__ hA, int N) {
  __shared__ float sW[9 * 128];
  __shared__ float sx[256 * 9];
  int tid = threadIdx.x;
  for (int q = tid; q < 9 * 128; q += 256) sW[q] = W1[q];
  int i = blockIdx.x * 256 + tid;
  float acc[9];
  if (i < N) {
    float di = dinv[i], sw = di * di;
#pragma unroll
    for (int f = 0; f < 9; ++f) acc[f] = x[(size_t)i * 9 + f] * sw;  // self-loop
    int rs = row_ptr[i], re = row_ptr[i + 1];
    for (int e = rs; e < re; ++e) {
      long long p = epack[e];
      float w = ep_w(p);
      const float* xp = x + (size_t)ep_src(p) * 9;
#pragma unroll
      for (int f = 0; f < 9; ++f) acc[f] = fmaf(xp[f], w, acc[f]);
    }
  } else {
#pragma unroll
    for (int f = 0; f < 9; ++f) acc[f] = 0.0f;
  }
#pragma unroll
  for (int f = 0; f < 9; ++f) sx[tid * 9 + f] = acc[f];  // stride 9: 2-way alias only (free)
  __syncthreads();
  // GEMV phase: thread owns one output column; W1 column hoisted to registers.
  int col = tid & 127, rsub = tid >> 7;
  float w9[9];
#pragma unroll
  for (int f = 0; f < 9; ++f) w9[f] = sW[f * 128 + col];
  float bias = b1[col];
  int base = blockIdx.x * 256;
  for (int j = 0; j < 128; ++j) {
    int rl = j * 2 + rsub;           // wave-uniform -> sx reads broadcast
    int row = base + rl;
    if (row >= N) break;             // wave-uniform break
    float s = bias;
#pragma unroll
    for (int f = 0; f < 9; ++f) s = fmaf(sx[rl * 9 + f], w9[f], s);
    hA[(size_t)row * 128 + col] = fmaxf(s, 0.0f);  // relu(conv1)
  }
}

// ---------------- layer 2 GEMM: t = h1 @ W2  (fp32, LDS-tiled 64x128) ----------------

__global__ __launch_bounds__(256) void gemm2_kernel(const float* __restrict__ hA,
                                                    const float* __restrict__ W2,
                                                    float* hB, int N) {
  __shared__ float Hs[32 * 68];    // [k][row], row-dim padded to 68
  __shared__ float Ws[32 * 128];   // [k][col]
  int tid = threadIdx.x;
  int rb = blockIdx.x * 64;
  int tcol = tid & 15, trow = tid >> 4;   // 16x16 threads; thread tile 4 rows x 8 cols
  float acc[4][8];
#pragma unroll
  for (int r = 0; r < 4; ++r)
#pragma unroll
    for (int c = 0; c < 8; ++c) acc[r][c] = 0.0f;

  for (int kc = 0; kc < 128; kc += 32) {
#pragma unroll
    for (int j = 0; j < 2; ++j) {        // stage Hs transposed: 512 float4
      int q = tid + j * 256;
      int row = q >> 3;
      int kk = (q & 7) * 4;
      float4 vv = make_float4(0.f, 0.f, 0.f, 0.f);
      int grow = rb + row;
      if (grow < N) vv = *(const float4*)&hA[(size_t)grow * 128 + kc + kk];
      Hs[(kk + 0) * 68 + row] = vv.x;
      Hs[(kk + 1) * 68 + row] = vv.y;
      Hs[(kk + 2) * 68 + row] = vv.z;
      Hs[(kk + 3) * 68 + row] = vv.w;
    }
#pragma unroll
    for (int j = 0; j < 4; ++j) {        // stage Ws: 1024 float4
      int q = tid + j * 256;
      int kr = q >> 5;
      int c4 = (q & 31) * 4;
      *(float4*)&Ws[kr * 128 + c4] = *(const float4*)&W2[(size_t)(kc + kr) * 128 + c4];
    }
    __syncthreads();
#pragma unroll 8
    for (int kk = 0; kk < 32; ++kk) {
      float4 a = *(const float4*)&Hs[kk * 68 + trow * 4];
      float4 b0 = *(const float4*)&Ws[kk * 128 + tcol * 8];
      float4 b1v = *(const float4*)&Ws[kk * 128 + tcol * 8 + 4];
      float av[4] = {a.x, a.y, a.z, a.w};
      float bv[8] = {b0.x, b0.y, b0.z, b0.w, b1v.x, b1v.y, b1v.z, b1v.w};
#pragma unroll
      for (int r = 0; r < 4; ++r)
#pragma unroll
        for (int c = 0; c < 8; ++c) acc[r][c] += av[r] * bv[c];
    }
    __syncthreads();
  }
#pragma unroll
  for (int r = 0; r < 4; ++r) {
    int row = rb + trow * 4 + r;
    if (row < N) {
      float4 o0 = make_float4(acc[r][0], acc[r][1], acc[r][2], acc[r][3]);
      float4 o1 = make_float4(acc[r][4], acc[r][5], acc[r][6], acc[r][7]);
      *(float4*)&hB[(size_t)row * 128 + tcol * 8] = o0;
      *(float4*)&hB[(size_t)row * 128 + tcol * 8 + 4] = o1;
    }
  }
}

// ---------------- layer 2 aggregation (wave/node, float2 row gather) fused with z = relu(.)·v ----------------

__global__ __launch_bounds__(256) void agg128_kernel(const float* __restrict__ t,
    const float* __restrict__ dinv, const int* __restrict__ row_ptr,
    const long long* __restrict__ epack, const float* __restrict__ b2,
    const float* __restrict__ v, float* __restrict__ z, int N) {
  int wave = threadIdx.x >> 6;
  int lane = threadIdx.x & 63;
  int i = blockIdx.x * 4 + wave;
  if (i >= N) return;                      // wave-uniform exit
  float di = dinv[i], sw = di * di;
  float2 self = *(const float2*)(t + (size_t)i * 128 + 2 * lane);
  float ax0 = self.x * sw, ay0 = self.y * sw;   // self-loop
  float ax1 = 0.0f, ay1 = 0.0f;
  int rs = row_ptr[i], re = row_ptr[i + 1];
  int e = rs;
  for (; e + 2 <= re; e += 2) {            // unroll x2: 2 independent 512B gathers in flight
    long long p0 = __builtin_nontemporal_load(&epack[e]);
    long long p1 = __builtin_nontemporal_load(&epack[e + 1]);
    float2 r0 = *(const float2*)(t + (size_t)ep_src(p0) * 128 + 2 * lane);
    float2 r1 = *(const float2*)(t + (size_t)ep_src(p1) * 128 + 2 * lane);
    float w0 = ep_w(p0), w1 = ep_w(p1);
    ax0 = fmaf(r0.x, w0, ax0); ay0 = fmaf(r0.y, w0, ay0);
    ax1 = fmaf(r1.x, w1, ax1); ay1 = fmaf(r1.y, w1, ay1);
  }
  if (e < re) {
    long long p = __builtin_nontemporal_load(&epack[e]);
    float2 r = *(const float2*)(t + (size_t)ep_src(p) * 128 + 2 * lane);
    float w = ep_w(p);
    ax0 = fmaf(r.x, w, ax0); ay0 = fmaf(r.y, w, ay0);
  }
  float h0 = fmaxf(ax0 + ax1 + b2[2 * lane], 0.0f);
  float h1 = fmaxf(ay0 + ay1 + b2[2 * lane + 1], 0.0f);
  float p = fmaf(h0, v[2 * lane], h1 * v[2 * lane + 1]);
#pragma unroll
  for (int off = 32; off > 0; off >>= 1) p += __shfl_down(p, off, 64);
  if (lane == 0) z[i] = p;                 // h2 never materialized
}

// ---------------- layer 3 (scalar) aggregation + mean-pool binning ----------------

__global__ void agg1_pool_kernel(const float* __restrict__ z, const float* __restrict__ dinv,
    const int* __restrict__ row_ptr, const long long* __restrict__ epack,
    const int* __restrict__ batch, float* gsum, float* gcnt, int N) {
  __shared__ float lsum[64];
  __shared__ float lcnt[64];
  int t = threadIdx.x;
  if (t < 64) { lsum[t] = 0.0f; lcnt[t] = 0.0f; }
  __syncthreads();
  int i = blockIdx.x * blockDim.x + t;
  if (i < N) {
    float di = dinv[i];
    float acc = z[i] * di * di;
    int rs = row_ptr[i], re = row_ptr[i + 1];
    for (int e = rs; e < re; ++e) {
      long long p = epack[e];
      acc = fmaf(z[ep_src(p)], ep_w(p), acc);
    }
    int g = batch[i];
    atomicAdd(&lsum[g], acc);
    atomicAdd(&lcnt[g], 1.0f);
  }
  __syncthreads();
  if (t < 64 && lcnt[t] != 0.0f) {
    atomicAdd(&gsum[t], lsum[t]);
    atomicAdd(&gcnt[t], lcnt[t]);
  }
}

__global__ void final_kernel(const float* __restrict__ gsum, const float* __restrict__ gcnt,
                             const float* __restrict__ c0, float* out, int G) {
  int g = threadIdx.x;
  if (g < G) out[g] = gsum[g] / fmaxf(gcnt[g], 1.0f) + c0[0];
}

// ---------------- launch ----------------

extern "C" void kernel_launch(void* const* d_in, const int* in_sizes, int n_in,
                              void* d_out, int out_size, void* d_ws, size_t ws_size,
                              hipStream_t stream) {
  const float* x      = (const float*)d_in[0];
  const int*   eidx   = (const int*)d_in[1];
  const int*   batch  = (const int*)d_in[2];
  const float* W1     = (const float*)d_in[3];
  const float* b1     = (const float*)d_in[4];
  const float* W2     = (const float*)d_in[5];
  const float* b2     = (const float*)d_in[6];
  const float* W3     = (const float*)d_in[7];
  const float* b3     = (const float*)d_in[8];
  const float* lin_w  = (const float*)d_in[9];
  const float* lin_b  = (const float*)d_in[10];
  float* out = (float*)d_out;

  int N = in_sizes[0] / 9;
  int E = in_sizes[1] / 2;
  int G = out_size;
  const int* src = eidx;
  const int* dst = eidx + E;

  char* w = (char*)d_ws;
  size_t off = 0;
  auto alloc = [&](size_t bytes) -> void* {
    void* p = w + off;
    off += bytes;
    off = (off + 255) & ~(size_t)255;
    return p;
  };

  int nb = (N + 255) / 256;
  float*     dinv   = (float*)    alloc((size_t)N * 4);        // deg, then dinv (in-place)
  int*       rowptr = (int*)      alloc((size_t)(N + 1) * 4);
  int*       cursor = (int*)      alloc((size_t)N * 4);        // indeg, then fill cursor
  int*       bsum   = (int*)      alloc((size_t)nb * 4);
  long long* epack  = (long long*)alloc((size_t)E * 8);        // interleaved (src, w)
  float*     hA     = (float*)    alloc((size_t)N * 128 * 4);  // h1
  float*     hB     = (float*)    alloc((size_t)N * 128 * 4);  // t = h1 @ W2
  float*     z      = (float*)    alloc((size_t)N * 4);
  float*     v      = (float*)    alloc(128 * 4);
  float*     c0     = (float*)    alloc(4);
  float*     gsum   = (float*)    alloc(64 * 4);
  float*     gcnt   = (float*)    alloc(64 * 4);

  zero_init_kernel<<<nb, 256, 0, stream>>>(dinv, gsum, gcnt, W3, b3, lin_w, lin_b, v, c0, N);
  deg_kernel<<<(E + 255) / 256, 256, 0, stream>>>(dst, dinv, E);
  dinv_bsum_kernel<<<nb, 256, 0, stream>>>(dinv, cursor, bsum, N);
  scan_bsum_kernel<<<1, 256, 0, stream>>>(bsum, nb);
  rowptr_kernel<<<nb, 256, 0, stream>>>(cursor, bsum, rowptr, cursor, N, E);
  fill_kernel<<<(E + 255) / 256, 256, 0, stream>>>(src, dst, dinv, cursor, epack, E);
  agg9_gemm1_kernel<<<nb, 256, 0, stream>>>(x, dinv, rowptr, epack, W1, b1, hA, N);
  gemm2_kernel<<<(N + 63) / 64, 256, 0, stream>>>(hA, W2, hB, N);
  agg128_kernel<<<(N + 3) / 4, 256, 0, stream>>>(hB, dinv, rowptr, epack, b2, v, z, N);
  agg1_pool_kernel<<<nb, 256, 0, stream>>>(z, dinv, rowptr, epack, batch, gsum, gcnt, N);
  final_kernel<<<1, 64, 0, stream>>>(gsum, gcnt, c0, out, G);
}

// Round 4
// 519.476 us; speedup vs baseline: 1.1634x; 1.0227x over previous
//
#include <hip/hip_runtime.h>
#include <math.h>

// ---------------- setup kernels ----------------

__global__ void deg_kernel(const int* __restrict__ dst, float* deg, int E) {
  int e = blockIdx.x * blockDim.x + threadIdx.x;
  if (e < E) atomicAdd(&deg[dst[e]], 1.0f);
}

// deg(float) -> indeg(int) + dinv = 1/sqrt(deg+1); per-block sum -> bsum; pad x -> xp (N x 12)
__global__ void dinv_bsum_pad_kernel(float* deg_dinv, int* indeg, int* bsum,
                                     const float* __restrict__ x, float* __restrict__ xp, int N) {
  __shared__ int s[256];
  int t = threadIdx.x;
  int i = blockIdx.x * 256 + t;
  int c = 0;
  if (i < N) {
    float cf = deg_dinv[i];
    c = (int)cf;                        // counts are small ints, exact in fp32
    indeg[i] = c;
    deg_dinv[i] = 1.0f / sqrtf(cf + 1.0f);
    const float* xr = x + (size_t)i * 9;
    float a0 = xr[0], a1 = xr[1], a2 = xr[2], a3 = xr[3], a4 = xr[4];
    float a5 = xr[5], a6 = xr[6], a7 = xr[7], a8 = xr[8];
    float* xo = xp + (size_t)i * 12;
    *(float4*)(xo + 0) = make_float4(a0, a1, a2, a3);
    *(float4*)(xo + 4) = make_float4(a4, a5, a6, a7);
    *(float4*)(xo + 8) = make_float4(a8, 0.0f, 0.0f, 0.0f);
  }
  s[t] = c;
  __syncthreads();
  for (int off = 128; off > 0; off >>= 1) {
    if (t < off) s[t] += s[t + off];
    __syncthreads();
  }
  if (t == 0) bsum[blockIdx.x] = s[0];
}

// single-block: exclusive scan of bsum + collapsed head (v = W3@lin_w, c0 = b3.lin_w + lin_b)
__global__ void scan_vc0_kernel(int* bsum, int nb,
                                const float* __restrict__ W3, const float* __restrict__ b3,
                                const float* __restrict__ lin_w, const float* __restrict__ lin_b,
                                float* v, float* c0) {
  __shared__ int s[1024];
  int t = threadIdx.x;
  for (int q = t; q < nb; q += blockDim.x) s[q] = bsum[q];
  if (t < 128) {
    float sv = 0.0f;
    for (int c = 0; c < 128; ++c) sv = fmaf(W3[t * 128 + c], lin_w[c], sv);
    v[t] = sv;
  } else if (t == 128) {
    float sv = 0.0f;
    for (int c = 0; c < 128; ++c) sv = fmaf(b3[c], lin_w[c], sv);
    c0[0] = sv + lin_b[0];
  }
  __syncthreads();
  if (t == 0) {
    int run = 0;
    for (int j = 0; j < nb; ++j) { int tmp = s[j]; s[j] = run; run += tmp; }
  }
  __syncthreads();
  for (int q = t; q < nb; q += blockDim.x) bsum[q] = s[q];
}

// indeg/cursor alias the same buffer: read own element, then overwrite. Safe.
__global__ void rowptr_kernel(const int* __restrict__ indeg, const int* __restrict__ bsum,
                              int* row_ptr, int* cursor, int N, int E) {
  __shared__ int s[256];
  int t = threadIdx.x;
  int i = blockIdx.x * 256 + t;
  int val = (i < N) ? indeg[i] : 0;
  s[t] = val;
  __syncthreads();
  for (int off = 1; off < 256; off <<= 1) {
    int x = (t >= off) ? s[t - off] : 0;
    __syncthreads();
    s[t] += x;
    __syncthreads();
  }
  int excl = s[t] - val + bsum[blockIdx.x];
  if (i < N) { row_ptr[i] = excl; cursor[i] = excl; }
  if (blockIdx.x == 0 && t == 0) row_ptr[N] = E;
}

// CSR fill with interleaved (src, weight) pack -> one 8B scattered store per edge
__global__ void fill_kernel(const int* __restrict__ src, const int* __restrict__ dst,
                            const float* __restrict__ dinv, int* cursor,
                            long long* __restrict__ epack, int E) {
  int e = blockIdx.x * blockDim.x + threadIdx.x;
  if (e < E) {
    int s = src[e], d = dst[e];
    int p = atomicAdd(&cursor[d], 1);
    unsigned int w = (unsigned int)__float_as_int(dinv[s] * dinv[d]);
    epack[p] = (long long)(((unsigned long long)w << 32) | (unsigned int)s);
  }
}

__device__ __forceinline__ int ep_src(long long p) { return (int)(unsigned int)p; }
__device__ __forceinline__ float ep_w(long long p) {
  return __int_as_float((int)(unsigned int)((unsigned long long)p >> 32));
}

// ---------------- layer 1 fused: xa = A_hat x (9-wide, padded-12 gathers), h1 = relu(xa@W1+b1) ----------------

__global__ __launch_bounds__(256) void agg9_gemm1_kernel(const float* __restrict__ xp,
    const float* __restrict__ dinv, const int* __restrict__ row_ptr,
    const long long* __restrict__ epack, const float* __restrict__ W1,
    const float* __restrict__ b1, float* __restrict__ hA, int N) {
  __shared__ float sW[9 * 128];
  __shared__ float sx[256 * 9];
  int tid = threadIdx.x;
  for (int q = tid; q < 9 * 128; q += 256) sW[q] = W1[q];
  int i = blockIdx.x * 256 + tid;
  float4 A0, A1, A2, B0, B1, B2;
  A0 = A1 = A2 = B0 = B1 = B2 = make_float4(0.f, 0.f, 0.f, 0.f);
  if (i < N) {
    float di = dinv[i], sw = di * di;
    const float4* xi = (const float4*)(xp + (size_t)i * 12);
    float4 s0 = xi[0], s1 = xi[1], s2 = xi[2];
    A0.x = s0.x * sw; A0.y = s0.y * sw; A0.z = s0.z * sw; A0.w = s0.w * sw;
    A1.x = s1.x * sw; A1.y = s1.y * sw; A1.z = s1.z * sw; A1.w = s1.w * sw;
    A2.x = s2.x * sw;
    int rs = row_ptr[i], re = row_ptr[i + 1];
    int e = rs;
    for (; e + 2 <= re; e += 2) {        // x2 unroll: 6 independent 16B gathers in flight
      long long p0 = __builtin_nontemporal_load(&epack[e]);
      long long p1 = __builtin_nontemporal_load(&epack[e + 1]);
      const float4* q0 = (const float4*)(xp + (size_t)ep_src(p0) * 12);
      const float4* q1 = (const float4*)(xp + (size_t)ep_src(p1) * 12);
      float4 r0 = q0[0], r1 = q0[1], r2 = q0[2];
      float4 u0 = q1[0], u1 = q1[1], u2 = q1[2];
      float w0 = ep_w(p0), w1 = ep_w(p1);
      A0.x = fmaf(r0.x, w0, A0.x); A0.y = fmaf(r0.y, w0, A0.y);
      A0.z = fmaf(r0.z, w0, A0.z); A0.w = fmaf(r0.w, w0, A0.w);
      A1.x = fmaf(r1.x, w0, A1.x); A1.y = fmaf(r1.y, w0, A1.y);
      A1.z = fmaf(r1.z, w0, A1.z); A1.w = fmaf(r1.w, w0, A1.w);
      A2.x = fmaf(r2.x, w0, A2.x);
      B0.x = fmaf(u0.x, w1, B0.x); B0.y = fmaf(u0.y, w1, B0.y);
      B0.z = fmaf(u0.z, w1, B0.z); B0.w = fmaf(u0.w, w1, B0.w);
      B1.x = fmaf(u1.x, w1, B1.x); B1.y = fmaf(u1.y, w1, B1.y);
      B1.z = fmaf(u1.z, w1, B1.z); B1.w = fmaf(u1.w, w1, B1.w);
      B2.x = fmaf(u2.x, w1, B2.x);
    }
    if (e < re) {
      long long p0 = __builtin_nontemporal_load(&epack[e]);
      const float4* q0 = (const float4*)(xp + (size_t)ep_src(p0) * 12);
      float4 r0 = q0[0], r1 = q0[1], r2 = q0[2];
      float w0 = ep_w(p0);
      A0.x = fmaf(r0.x, w0, A0.x); A0.y = fmaf(r0.y, w0, A0.y);
      A0.z = fmaf(r0.z, w0, A0.z); A0.w = fmaf(r0.w, w0, A0.w);
      A1.x = fmaf(r1.x, w0, A1.x); A1.y = fmaf(r1.y, w0, A1.y);
      A1.z = fmaf(r1.z, w0, A1.z); A1.w = fmaf(r1.w, w0, A1.w);
      A2.x = fmaf(r2.x, w0, A2.x);
    }
  }
  float* so = sx + tid * 9;            // stride 9: worst 2-way alias (free)
  so[0] = A0.x + B0.x; so[1] = A0.y + B0.y; so[2] = A0.z + B0.z; so[3] = A0.w + B0.w;
  so[4] = A1.x + B1.x; so[5] = A1.y + B1.y; so[6] = A1.z + B1.z; so[7] = A1.w + B1.w;
  so[8] = A2.x + B2.x;
  __syncthreads();
  // GEMV phase: thread owns one output column; W1 column hoisted to registers.
  int col = tid & 127, rsub = tid >> 7;
  float w9[9];
#pragma unroll
  for (int f = 0; f < 9; ++f) w9[f] = sW[f * 128 + col];
  float bias = b1[col];
  int base = blockIdx.x * 256;
  for (int j = 0; j < 128; ++j) {
    int rl = j * 2 + rsub;             // wave-uniform -> sx reads broadcast
    int row = base + rl;
    if (row >= N) break;               // wave-uniform break
    float s = bias;
#pragma unroll
    for (int f = 0; f < 9; ++f) s = fmaf(sx[rl * 9 + f], w9[f], s);
    hA[(size_t)row * 128 + col] = fmaxf(s, 0.0f);  // relu(conv1)
  }
}

// ---------------- layer 2 GEMM: t = h1 @ W2  (fp32, 128x128 block, 8x8 thread tile) ----------------

__global__ __launch_bounds__(256, 4) void gemm2_kernel(const float* __restrict__ hA,
                                                       const float* __restrict__ W2,
                                                       float* __restrict__ hB, int N) {
  __shared__ float Hs[32 * 132];   // [k][row], stride 132 (16B-aligned rows)
  __shared__ float Ws[32 * 128];   // [k][col]
  int tid = threadIdx.x;
  int rb = blockIdx.x * 128;
  int tr = tid >> 4, tc = tid & 15;   // 16x16 threads; 8 rows x 8 cols each
  float acc[8][8];
#pragma unroll
  for (int r = 0; r < 8; ++r)
#pragma unroll
    for (int c = 0; c < 8; ++c) acc[r][c] = 0.0f;

  for (int kc = 0; kc < 128; kc += 32) {
#pragma unroll
    for (int j = 0; j < 4; ++j) {      // stage Hs transposed: 1024 float4 loads
      int q = tid + j * 256;
      int row = q >> 3;
      int kk = (q & 7) * 4;
      float4 vv = make_float4(0.f, 0.f, 0.f, 0.f);
      int grow = rb + row;
      if (grow < N) vv = *(const float4*)&hA[(size_t)grow * 128 + kc + kk];
      Hs[(kk + 0) * 132 + row] = vv.x;
      Hs[(kk + 1) * 132 + row] = vv.y;
      Hs[(kk + 2) * 132 + row] = vv.z;
      Hs[(kk + 3) * 132 + row] = vv.w;
    }
#pragma unroll
    for (int j = 0; j < 4; ++j) {      // stage Ws: 1024 float4
      int q = tid + j * 256;
      int kr = q >> 5;
      int c4 = (q & 31) * 4;
      *(float4*)&Ws[kr * 128 + c4] = *(const float4*)&W2[(size_t)(kc + kr) * 128 + c4];
    }
    __syncthreads();
#pragma unroll 4
    for (int kk = 0; kk < 32; ++kk) {
      float4 a0 = *(const float4*)&Hs[kk * 132 + tr * 8];
      float4 a1 = *(const float4*)&Hs[kk * 132 + tr * 8 + 4];
      float4 b0 = *(const float4*)&Ws[kk * 128 + tc * 8];
      float4 b1 = *(const float4*)&Ws[kk * 128 + tc * 8 + 4];
      float av[8] = {a0.x, a0.y, a0.z, a0.w, a1.x, a1.y, a1.z, a1.w};
      float bv[8] = {b0.x, b0.y, b0.z, b0.w, b1.x, b1.y, b1.z, b1.w};
#pragma unroll
      for (int r = 0; r < 8; ++r)
#pragma unroll
        for (int c = 0; c < 8; ++c) acc[r][c] = fmaf(av[r], bv[c], acc[r][c]);
    }
    __syncthreads();
  }
#pragma unroll
  for (int r = 0; r < 8; ++r) {
    int row = rb + tr * 8 + r;
    if (row < N) {
      *(float4*)&hB[(size_t)row * 128 + tc * 8] =
          make_float4(acc[r][0], acc[r][1], acc[r][2], acc[r][3]);
      *(float4*)&hB[(size_t)row * 128 + tc * 8 + 4] =
          make_float4(acc[r][4], acc[r][5], acc[r][6], acc[r][7]);
    }
  }
}

// ---------------- layer 2 aggregation: half-wave float4 gather, fused z = relu(.)·v ----------------

__global__ __launch_bounds__(256) void agg128_kernel(const float* __restrict__ t,
    const float* __restrict__ dinv, const int* __restrict__ row_ptr,
    const long long* __restrict__ epack, const float* __restrict__ b2,
    const float* __restrict__ v, float* __restrict__ z, int N) {
  int wave = threadIdx.x >> 6;
  int lane = threadIdx.x & 63;
  int half = lane >> 5;                // each 32-lane half gathers one full 512B row
  int l32  = lane & 31;
  int i = blockIdx.x * 4 + wave;
  if (i >= N) return;                  // wave-uniform exit
  float di = dinv[i], sw = di * di;
  float4 s4 = *((const float4*)(t + (size_t)i * 128) + l32);
  float m = half ? 0.0f : sw;          // self-loop counted once (lower half)
  float4 a0 = make_float4(s4.x * m, s4.y * m, s4.z * m, s4.w * m);
  float4 a1 = make_float4(0.f, 0.f, 0.f, 0.f);
  int rs = row_ptr[i], re = row_ptr[i + 1];
  int e = rs;
  for (; e + 4 <= re; e += 4) {        // 4 edges/iter, 2 b128 gathers in flight
    long long pA = __builtin_nontemporal_load(&epack[e + half]);
    long long pB = __builtin_nontemporal_load(&epack[e + 2 + half]);
    float4 rA = *((const float4*)(t + (size_t)ep_src(pA) * 128) + l32);
    float4 rB = *((const float4*)(t + (size_t)ep_src(pB) * 128) + l32);
    float wA = ep_w(pA), wB = ep_w(pB);
    a0.x = fmaf(rA.x, wA, a0.x); a0.y = fmaf(rA.y, wA, a0.y);
    a0.z = fmaf(rA.z, wA, a0.z); a0.w = fmaf(rA.w, wA, a0.w);
    a1.x = fmaf(rB.x, wB, a1.x); a1.y = fmaf(rB.y, wB, a1.y);
    a1.z = fmaf(rB.z, wB, a1.z); a1.w = fmaf(rB.w, wB, a1.w);
  }
  if (e + 2 <= re) {
    long long p = __builtin_nontemporal_load(&epack[e + half]);
    float4 r = *((const float4*)(t + (size_t)ep_src(p) * 128) + l32);
    float w = ep_w(p);
    a0.x = fmaf(r.x, w, a0.x); a0.y = fmaf(r.y, w, a0.y);
    a0.z = fmaf(r.z, w, a0.z); a0.w = fmaf(r.w, w, a0.w);
    e += 2;
  }
  if (e < re) {                        // odd tail: both halves take w/2 (exact)
    long long p = __builtin_nontemporal_load(&epack[e]);
    float4 r = *((const float4*)(t + (size_t)ep_src(p) * 128) + l32);
    float w = ep_w(p) * 0.5f;
    a1.x = fmaf(r.x, w, a1.x); a1.y = fmaf(r.y, w, a1.y);
    a1.z = fmaf(r.z, w, a1.z); a1.w = fmaf(r.w, w, a1.w);
  }
  float4 a = make_float4(a0.x + a1.x, a0.y + a1.y, a0.z + a1.z, a0.w + a1.w);
  a.x += __shfl_down(a.x, 32, 64);     // combine halves -> lanes 0..31 hold full sums
  a.y += __shfl_down(a.y, 32, 64);
  a.z += __shfl_down(a.z, 32, 64);
  a.w += __shfl_down(a.w, 32, 64);
  float4 bb = *((const float4*)b2 + l32);
  float4 vv = *((const float4*)v + l32);
  float p = fmaxf(a.x + bb.x, 0.f) * vv.x + fmaxf(a.y + bb.y, 0.f) * vv.y
          + fmaxf(a.z + bb.z, 0.f) * vv.z + fmaxf(a.w + bb.w, 0.f) * vv.w;
#pragma unroll
  for (int off = 16; off > 0; off >>= 1) p += __shfl_down(p, off, 64);
  if (lane == 0) z[i] = p;             // h2 never materialized
}

// ---------------- layer 3 (scalar) aggregation + mean-pool binning ----------------

__global__ void agg1_pool_kernel(const float* __restrict__ z, const float* __restrict__ dinv,
    const int* __restrict__ row_ptr, const long long* __restrict__ epack,
    const int* __restrict__ batch, float* gsum, float* gcnt, int N) {
  __shared__ float lsum[64];
  __shared__ float lcnt[64];
  int t = threadIdx.x;
  if (t < 64) { lsum[t] = 0.0f; lcnt[t] = 0.0f; }
  __syncthreads();
  int i = blockIdx.x * blockDim.x + t;
  if (i < N) {
    float di = dinv[i];
    float acc = z[i] * di * di;
    int rs = row_ptr[i], re = row_ptr[i + 1];
    for (int e = rs; e < re; ++e) {
      long long p = epack[e];
      acc = fmaf(z[ep_src(p)], ep_w(p), acc);
    }
    int g = batch[i];
    atomicAdd(&lsum[g], acc);
    atomicAdd(&lcnt[g], 1.0f);
  }
  __syncthreads();
  if (t < 64 && lcnt[t] != 0.0f) {
    atomicAdd(&gsum[t], lsum[t]);
    atomicAdd(&gcnt[t], lcnt[t]);
  }
}

__global__ void final_kernel(const float* __restrict__ gsum, const float* __restrict__ gcnt,
                             const float* __restrict__ c0, float* out, int G) {
  int g = threadIdx.x;
  if (g < G) out[g] = gsum[g] / fmaxf(gcnt[g], 1.0f) + c0[0];
}

// ---------------- launch ----------------

extern "C" void kernel_launch(void* const* d_in, const int* in_sizes, int n_in,
                              void* d_out, int out_size, void* d_ws, size_t ws_size,
                              hipStream_t stream) {
  const float* x      = (const float*)d_in[0];
  const int*   eidx   = (const int*)d_in[1];
  const int*   batch  = (const int*)d_in[2];
  const float* W1     = (const float*)d_in[3];
  const float* b1     = (const float*)d_in[4];
  const float* W2     = (const float*)d_in[5];
  const float* b2     = (const float*)d_in[6];
  const float* W3     = (const float*)d_in[7];
  const float* b3     = (const float*)d_in[8];
  const float* lin_w  = (const float*)d_in[9];
  const float* lin_b  = (const float*)d_in[10];
  float* out = (float*)d_out;

  int N = in_sizes[0] / 9;
  int E = in_sizes[1] / 2;
  int G = out_size;
  const int* src = eidx;
  const int* dst = eidx + E;

  char* w = (char*)d_ws;
  size_t off = 0;
  auto alloc = [&](size_t bytes) -> void* {
    void* p = w + off;
    off += bytes;
    off = (off + 255) & ~(size_t)255;
    return p;
  };

  int nb = (N + 255) / 256;
  // zero-init region (one memset): deg, gsum, gcnt
  float*     dinv   = (float*)    alloc((size_t)N * 4);        // deg, then dinv (in-place)
  float*     gsum   = (float*)    alloc(64 * 4);
  float*     gcnt   = (float*)    alloc(64 * 4);
  size_t zspan = off;                                          // bytes from ws start
  int*       rowptr = (int*)      alloc((size_t)(N + 1) * 4);
  int*       cursor = (int*)      alloc((size_t)N * 4);        // indeg, then fill cursor
  int*       bsum   = (int*)      alloc((size_t)nb * 4);
  long long* epack  = (long long*)alloc((size_t)E * 8);        // interleaved (src, w)
  float*     hA     = (float*)    alloc((size_t)N * 128 * 4);  // h1
  float*     hB     = (float*)    alloc((size_t)N * 128 * 4);  // xp (N x 12) first, then t = h1@W2
  float*     z      = (float*)    alloc((size_t)N * 4);
  float*     v      = (float*)    alloc(128 * 4);
  float*     c0     = (float*)    alloc(4);
  float*     xp     = hB;                                      // alias: dead before gemm2 writes hB

  hipMemsetAsync(d_ws, 0, zspan, stream);
  deg_kernel<<<(E + 255) / 256, 256, 0, stream>>>(dst, dinv, E);
  dinv_bsum_pad_kernel<<<nb, 256, 0, stream>>>(dinv, cursor, bsum, x, xp, N);
  scan_vc0_kernel<<<1, 256, 0, stream>>>(bsum, nb, W3, b3, lin_w, lin_b, v, c0);
  rowptr_kernel<<<nb, 256, 0, stream>>>(cursor, bsum, rowptr, cursor, N, E);
  fill_kernel<<<(E + 255) / 256, 256, 0, stream>>>(src, dst, dinv, cursor, epack, E);
  agg9_gemm1_kernel<<<nb, 256, 0, stream>>>(xp, dinv, rowptr, epack, W1, b1, hA, N);
  gemm2_kernel<<<(N + 127) / 128, 256, 0, stream>>>(hA, W2, hB, N);
  agg128_kernel<<<(N + 3) / 4, 256, 0, stream>>>(hB, dinv, rowptr, epack, b2, v, z, N);
  agg1_pool_kernel<<<nb, 256, 0, stream>>>(z, dinv, rowptr, epack, batch, gsum, gcnt, N);
  final_kernel<<<1, 64, 0, stream>>>(gsum, gcnt, c0, out, G);
}